// Round 1
// baseline (3390.420 us; speedup 1.0000x reference)
//
#include <hip/hip_runtime.h>
#include <math.h>

// Problem constants (fixed by reference)
#define MUL0    32
#define MUL1    16
#define RBFD    16
#define HIDD    64
#define OFF1    1024      // MUL0*MUL0
#define OFF2    1536      // +MUL0*MUL1
#define OFF3    1792      // +MUL1*MUL1
#define WNUMEL  2304      // +MUL1*MUL0
#define FDIM    80        // MUL0 + 3*MUL1
#define CPATH   0.14433756729740643f   // 1/sqrt(48)
#define C110    0.57735026918962576f   // 1/sqrt(3)

#define EPB 16            // edges per block (E=200000 divisible by 16)

__device__ __forceinline__ float silu(float v) {
    return v / (1.0f + __expf(-v));
}

// ---------------------------------------------------------------------------
// Kernel 0: transpose w3[k][c] (64 x 2304) -> w3t[c][k] (2304 x 64) so the
// per-column dot over k is contiguous float4 loads.
// ---------------------------------------------------------------------------
__global__ void k_transpose_w3(const float* __restrict__ w3,
                               float* __restrict__ w3t) {
    int idx = blockIdx.x * 256 + threadIdx.x;
    if (idx >= HIDD * WNUMEL) return;
    int c = idx >> 6;      // 0..2303
    int k = idx & 63;      // 0..63
    w3t[idx] = w3[k * WNUMEL + c];
}

// ---------------------------------------------------------------------------
// Kernel 1: per-edge MLP + fused bilinear contraction + atomic scatter-add.
// Block = 256 threads handles EPB=16 edges. Thread (el = tid&15, tg = tid>>4)
// owns edge el and tasks {tg, tg+16 (scalar outputs), tg (vector output)}.
// agg == d_out (reused as the segment-sum accumulator; zeroed beforehand).
// ---------------------------------------------------------------------------
__global__ __launch_bounds__(256)
void k_edge(const float* __restrict__ x,
            const int*   __restrict__ esrc,
            const int*   __restrict__ edst,
            const float* __restrict__ esh,
            const float* __restrict__ erbf,
            const float* __restrict__ w1,
            const float* __restrict__ b1,
            const float* __restrict__ w2,
            const float* __restrict__ b2,
            const float* __restrict__ w3t,
            const float* __restrict__ b3,
            float* __restrict__ agg,
            float* __restrict__ deg,
            int E)
{
    __shared__ float s_rbf[EPB][17];   // padded odd strides -> no bank conflicts
    __shared__ float s_h1 [EPB][65];
    __shared__ float s_h  [EPB][65];
    __shared__ float s_xs [EPB][33];
    __shared__ float s_xv [EPB][49];
    __shared__ float s_fs [EPB][49];   // scalar-path feature vector (48)
    __shared__ float s_sh [EPB][4];
    __shared__ int   s_src[EPB];
    __shared__ int   s_dst[EPB];

    const int tid = threadIdx.x;
    const int eb  = blockIdx.x * EPB;
    const int el  = tid & 15;
    const int tg  = tid >> 4;          // 0..15

    // ---- stage edge metadata ----
    if (tid < EPB) {
        int eg = eb + tid;
        s_src[tid] = (eg < E) ? esrc[eg] : 0;
        s_dst[tid] = (eg < E) ? edst[eg] : 0;
    }
    if (tid < EPB * 4) {
        int le = tid >> 2, c = tid & 3;
        int eg = eb + le;
        s_sh[le][c] = (eg < E) ? esh[eg * 4 + c] : 0.0f;
    }
    {
        int le = tid >> 4, i = tid & 15;
        int eg = eb + le;
        s_rbf[le][i] = (eg < E) ? erbf[eg * RBFD + i] : 0.0f;
    }
    __syncthreads();

    // ---- gather source-node features (needs s_src) ----
    for (int idx = tid; idx < EPB * FDIM; idx += 256) {
        int le = idx / FDIM, j = idx - le * FDIM;
        float v = x[(size_t)s_src[le] * FDIM + j];
        if (j < MUL0) s_xs[le][j] = v;
        else          s_xv[le][j - MUL0] = v;
    }
    // ---- MLP layer 1: h1 = silu(rbf @ w1 + b1); thread computes 4 cols ----
    {
        const int j0 = tg * 4;
        float a0 = b1[j0], a1 = b1[j0+1], a2 = b1[j0+2], a3 = b1[j0+3];
        #pragma unroll
        for (int i = 0; i < RBFD; ++i) {
            float r = s_rbf[el][i];
            const float* wr = w1 + i * HIDD + j0;
            a0 += r * wr[0]; a1 += r * wr[1]; a2 += r * wr[2]; a3 += r * wr[3];
        }
        s_h1[el][j0]   = silu(a0);
        s_h1[el][j0+1] = silu(a1);
        s_h1[el][j0+2] = silu(a2);
        s_h1[el][j0+3] = silu(a3);
    }
    __syncthreads();

    // ---- MLP layer 2: h = silu(h1 @ w2 + b2) ----
    {
        const int j0 = tg * 4;
        float a0 = b2[j0], a1 = b2[j0+1], a2 = b2[j0+2], a3 = b2[j0+3];
        #pragma unroll
        for (int i = 0; i < HIDD; ++i) {
            float r = s_h1[el][i];
            const float* wr = w2 + i * HIDD + j0;
            a0 += r * wr[0]; a1 += r * wr[1]; a2 += r * wr[2]; a3 += r * wr[3];
        }
        s_h[el][j0]   = silu(a0);
        s_h[el][j0+1] = silu(a1);
        s_h[el][j0+2] = silu(a2);
        s_h[el][j0+3] = silu(a3);
    }
    // ---- scalar-path features: fs[i<32] = xs_i*sh_s ; fs[32+i] = C110*(xv_i . sh_v)
    for (int idx = tid; idx < EPB * 48; idx += 256) {
        int le = idx / 48, i = idx - le * 48;
        float f;
        if (i < 32) {
            f = s_xs[le][i] * s_sh[le][0];
        } else {
            int ii = i - 32;
            f = C110 * (s_xv[le][ii*3+0] * s_sh[le][1]
                      + s_xv[le][ii*3+1] * s_sh[le][2]
                      + s_xv[le][ii*3+2] * s_sh[le][3]);
        }
        s_fs[le][i] = f;
    }
    __syncthreads();

    // ---- main contraction: each thread owns edge el, output group tg ----
    float h[HIDD];
    #pragma unroll
    for (int k = 0; k < HIDD; ++k) h[k] = s_h[el][k];

    const float shs  = s_sh[el][0];
    const float shv0 = s_sh[el][1];
    const float shv1 = s_sh[el][2];
    const float shv2 = s_sh[el][3];
    const bool  valid = (eb + el) < E;
    float* aggrow = agg + (size_t)s_dst[el] * FDIM;

    // W[e][c] = b3[c] + sum_k h[k] * w3t[c][k]   (64-wide dot, float4 loads)
    auto dotw = [&](int c) -> float {
        const float4* wp = (const float4*)(w3t + (size_t)c * HIDD);
        float a0 = b3[c], a1 = 0.f, a2 = 0.f, a3 = 0.f;
        #pragma unroll
        for (int kk = 0; kk < 16; ++kk) {
            float4 w = wp[kk];
            a0 += h[4*kk+0] * w.x;
            a1 += h[4*kk+1] * w.y;
            a2 += h[4*kk+2] * w.z;
            a3 += h[4*kk+3] * w.w;
        }
        return (a0 + a1) + (a2 + a3);
    };

    // Scalar outputs o = tg and tg+16:
    // out_s[o] = sum_{i<32} fs[i]*W1[i,o] + sum_{i<16} fs[32+i]*W4[i,o]
    #pragma unroll
    for (int rep = 0; rep < 2; ++rep) {
        const int o = tg + rep * 16;
        float acc = 0.f;
        for (int i = 0; i < 32; ++i)
            acc += s_fs[el][i] * dotw(i * MUL0 + o);          // W1: c = i*32+o
        for (int i = 0; i < 16; ++i)
            acc += s_fs[el][32 + i] * dotw(OFF3 + i * MUL0 + o); // W4
        if (valid) atomicAdd(&aggrow[o], CPATH * acc);
    }
    // Vector output o = tg:
    // out_v[o,d] = sh_v[d]*sum_i xs_i*W2[i,o] + sh_s*sum_i xv[i,d]*W3[i,o]
    {
        const int o = tg;
        float t2 = 0.f, t30 = 0.f, t31 = 0.f, t32 = 0.f;
        for (int i = 0; i < 32; ++i)
            t2 += s_xs[el][i] * dotw(OFF1 + i * MUL1 + o);     // W2: c = O1+i*16+o
        for (int i = 0; i < 16; ++i) {
            float wv = dotw(OFF2 + i * MUL1 + o);              // W3
            t30 += s_xv[el][i*3+0] * wv;
            t31 += s_xv[el][i*3+1] * wv;
            t32 += s_xv[el][i*3+2] * wv;
        }
        if (valid) {
            atomicAdd(&aggrow[MUL0 + o*3 + 0], CPATH * (shv0 * t2 + shs * t30));
            atomicAdd(&aggrow[MUL0 + o*3 + 1], CPATH * (shv1 * t2 + shs * t31));
            atomicAdd(&aggrow[MUL0 + o*3 + 2], CPATH * (shv2 * t2 + shs * t32));
        }
    }
    if (tg == 0 && valid) atomicAdd(&deg[s_dst[el]], 1.0f);
}

// ---------------------------------------------------------------------------
// Kernel 2: per-node epilogue. d_out currently holds agg (pre-normalization).
// out[n] = irrep_linear(x[n], ws_self, wv_self)
//        + irrep_linear(agg[n]/max(deg,1), ws_out, wv_out)
// One thread per node; thread reads its row, then overwrites it. Safe.
// ---------------------------------------------------------------------------
__global__ __launch_bounds__(256)
void k_node(const float* __restrict__ x,
            const float* __restrict__ deg,
            const float* __restrict__ ws_self,
            const float* __restrict__ wv_self,
            const float* __restrict__ ws_out,
            const float* __restrict__ wv_out,
            float* __restrict__ out,
            int N)
{
    int n = blockIdx.x * 256 + threadIdx.x;
    if (n >= N) return;

    float xr[FDIM], ar[FDIM];
    const float4* xp = (const float4*)(x + (size_t)n * FDIM);
    float4*       op = (float4*)(out + (size_t)n * FDIM);
    const float inv = 1.0f / fmaxf(deg[n], 1.0f);

    #pragma unroll
    for (int q = 0; q < FDIM / 4; ++q) {
        float4 a = op[q];
        float4 xv4 = xp[q];
        ar[4*q+0] = a.x * inv; ar[4*q+1] = a.y * inv;
        ar[4*q+2] = a.z * inv; ar[4*q+3] = a.w * inv;
        xr[4*q+0] = xv4.x; xr[4*q+1] = xv4.y;
        xr[4*q+2] = xv4.z; xr[4*q+3] = xv4.w;
    }

    // scalar block: out[:, o] = sum_i xr[i]*ws_self[i,o] + ar[i]*ws_out[i,o]
    for (int o = 0; o < MUL0; ++o) {
        float acc = 0.f;
        #pragma unroll
        for (int i = 0; i < MUL0; ++i)
            acc += xr[i] * ws_self[i * MUL0 + o] + ar[i] * ws_out[i * MUL0 + o];
        out[(size_t)n * FDIM + o] = acc;
    }
    // vector block: out[:, 32+o*3+d] = sum_i xv[i,d]*wv_self[i,o] + av[i,d]*wv_out[i,o]
    for (int o = 0; o < MUL1; ++o) {
        float a0 = 0.f, a1 = 0.f, a2 = 0.f;
        #pragma unroll
        for (int i = 0; i < MUL1; ++i) {
            float wsf = wv_self[i * MUL1 + o];
            float wof = wv_out [i * MUL1 + o];
            a0 += xr[MUL0 + i*3 + 0] * wsf + ar[MUL0 + i*3 + 0] * wof;
            a1 += xr[MUL0 + i*3 + 1] * wsf + ar[MUL0 + i*3 + 1] * wof;
            a2 += xr[MUL0 + i*3 + 2] * wsf + ar[MUL0 + i*3 + 2] * wof;
        }
        out[(size_t)n * FDIM + MUL0 + o*3 + 0] = a0;
        out[(size_t)n * FDIM + MUL0 + o*3 + 1] = a1;
        out[(size_t)n * FDIM + MUL0 + o*3 + 2] = a2;
    }
}

// ---------------------------------------------------------------------------
extern "C" void kernel_launch(void* const* d_in, const int* in_sizes, int n_in,
                              void* d_out, int out_size, void* d_ws, size_t ws_size,
                              hipStream_t stream)
{
    const float* x       = (const float*)d_in[0];
    const int*   esrc    = (const int*)  d_in[1];
    const int*   edst    = (const int*)  d_in[2];
    const float* esh     = (const float*)d_in[3];
    const float* erbf    = (const float*)d_in[4];
    const float* w1      = (const float*)d_in[5];
    const float* b1      = (const float*)d_in[6];
    const float* w2      = (const float*)d_in[7];
    const float* b2      = (const float*)d_in[8];
    const float* w3      = (const float*)d_in[9];
    const float* b3      = (const float*)d_in[10];
    const float* ws_self = (const float*)d_in[11];
    const float* wv_self = (const float*)d_in[12];
    const float* ws_out  = (const float*)d_in[13];
    const float* wv_out  = (const float*)d_in[14];

    const int N = in_sizes[0] / FDIM;
    const int E = in_sizes[1];

    // ws layout: [deg: N floats (aligned to 64)] [w3t: 2304*64 floats]
    float* deg = (float*)d_ws;
    float* w3t = (float*)d_ws + ((size_t)(N + 63) / 64) * 64;

    // Zero the aggregation buffer (d_out doubles as agg) and degrees.
    hipMemsetAsync(d_out, 0, (size_t)out_size * sizeof(float), stream);
    hipMemsetAsync(deg, 0, (size_t)N * sizeof(float), stream);

    k_transpose_w3<<<(HIDD * WNUMEL + 255) / 256, 256, 0, stream>>>(w3, w3t);

    k_edge<<<(E + EPB - 1) / EPB, 256, 0, stream>>>(
        x, esrc, edst, esh, erbf, w1, b1, w2, b2, w3t, b3,
        (float*)d_out, deg, E);

    k_node<<<(N + 255) / 256, 256, 0, stream>>>(
        x, deg, ws_self, wv_self, ws_out, wv_out, (float*)d_out, N);
}

// Round 2
// 381.559 us; speedup vs baseline: 8.8857x; 8.8857x over previous
//
#include <hip/hip_runtime.h>
#include <math.h>

// Problem constants (fixed by reference)
#define MUL0    32
#define MUL1    16
#define RBFD    16
#define HIDD    64
#define OFF1    1024      // MUL0*MUL0
#define OFF2    1536      // +MUL0*MUL1
#define OFF3    1792      // +MUL1*MUL1
#define WNUMEL  2304      // +MUL1*MUL0
#define FDIM    80        // MUL0 + 3*MUL1
#define CPATH   0.14433756729740643f   // 1/sqrt(48)
#define C110    0.57735026918962576f   // 1/sqrt(3)

#define TE 64             // edges per block (E=200000 divisible? 200000/64=3125 exact)
#define NCT 144           // 2304/16 column tiles

typedef float  f32x4  __attribute__((ext_vector_type(4)));
typedef short  short8 __attribute__((ext_vector_type(8)));

__device__ __forceinline__ float silu(float v) {
    return v / (1.0f + __expf(-v));
}

// fp32 -> bf16 with round-to-nearest-even
__device__ __forceinline__ unsigned short f2bf(float f) {
    unsigned int u = __float_as_uint(f);
    u += 0x7fffu + ((u >> 16) & 1u);
    return (unsigned short)(u >> 16);
}

__device__ __forceinline__ f32x4 mfma16(short8 a, short8 b, f32x4 c) {
    return __builtin_amdgcn_mfma_f32_16x16x32_bf16(a, b, c, 0, 0, 0);
}

// ---------------------------------------------------------------------------
// Kernel 0: pack w3 (fp32 [64][2304], k-major) into bf16 B-fragments.
// Fragment f = ct*2 + kh (ct: 16-col tile, kh: K-half). Element
// w3b[f*512 + l*8 + j] = bf16( w3[(kh*32 + 8*(l>>4) + j) * 2304 + ct*16 + (l&15)] )
// so a lane's 8 bf16 (16B) are one global_load_dwordx4.
// ---------------------------------------------------------------------------
__global__ void k_prep_w3b(const float* __restrict__ w3,
                           unsigned short* __restrict__ w3b) {
    int idx = blockIdx.x * 256 + threadIdx.x;
    if (idx >= NCT * 2 * 64 * 8) return;
    int j  = idx & 7;
    int l  = (idx >> 3) & 63;
    int kh = (idx >> 9) & 1;
    int ct = idx >> 10;
    int k = kh * 32 + 8 * (l >> 4) + j;
    int c = ct * 16 + (l & 15);
    w3b[idx] = f2bf(w3[k * WNUMEL + c]);
}

// ---------------------------------------------------------------------------
// Kernel 1: per-edge MLP (fp32) + MFMA W-tiles fused with feature contraction
// + atomic scatter into agg (= d_out, pre-zeroed).
// Block: 256 threads = 4 waves; TE=64 edges; each wave owns 16 edges.
// ---------------------------------------------------------------------------
__global__ __launch_bounds__(256)
void k_edge(const float* __restrict__ x,
            const int*   __restrict__ esrc,
            const int*   __restrict__ edst,
            const float* __restrict__ esh,
            const float* __restrict__ erbf,
            const float* __restrict__ w1,
            const float* __restrict__ b1,
            const float* __restrict__ w2,
            const float* __restrict__ b2,
            const unsigned short* __restrict__ w3b,
            const float* __restrict__ b3,
            float* __restrict__ agg,
            float* __restrict__ deg)
{
    // Manual LDS layout (bytes):
    //   [0, 32768)      features:  fsT [4][48][16] f32 @0 (12288)
    //                              xsT [4][32][16] f32 @12288 (8192)
    //                              xvT [4][3][16][16] f32 @20480 (12288)
    //   [0, 16640)      (ALIAS, MLP phase only) s_h1 [64][65] f32
    //   [32768, 41984)  s_hb [64][72] ushort (bf16 h, A-fragment source)
    //   [41984, 43008)  s_sh [64][4] f32
    //   [43008, 43520)  s_src[64], s_dst[64] int
    __shared__ alignas(16) char smem[43520];
    float*  s_fsT = (float*)smem;                    // w*768 + i*16 + e
    float*  s_xsT = (float*)(smem + 12288);          // w*512 + i*16 + e
    float*  s_xvT = (float*)(smem + 20480);          // w*768 + d*256 + i*16 + e
    float*  s_h1  = (float*)smem;                    // el*65 + col   (alias)
    unsigned short* s_hb = (unsigned short*)(smem + 32768); // el*72 + k
    float*  s_sh  = (float*)(smem + 41984);          // el*4 + c
    int*    s_src = (int*)(smem + 43008);
    int*    s_dst = s_src + 64;

    const int tid = threadIdx.x;
    const int eb  = blockIdx.x * TE;

    // ---- phase 0: stage edge metadata ----
    if (tid < TE) {
        s_src[tid] = esrc[eb + tid];
        s_dst[tid] = edst[eb + tid];
    }
    s_sh[tid] = esh[eb * 4 + tid];    // 256 = TE*4 floats, coalesced
    __syncthreads();

    const int el = tid & 63;
    const int q  = tid >> 6;          // 0..3
    const int j0 = q * 16;

    // ---- phase 1: MLP layer 1 -> s_h1 (thread: edge el, cols j0..j0+15) ----
    {
        float acc[16];
        #pragma unroll
        for (int jj = 0; jj < 16; ++jj) acc[jj] = b1[j0 + jj];
        const float* rbf = erbf + (size_t)(eb + el) * RBFD;
        #pragma unroll
        for (int v = 0; v < 4; ++v) {
            f32x4 r4 = *(const f32x4*)(rbf + v * 4);
            #pragma unroll
            for (int c = 0; c < 4; ++c) {
                float r = r4[c];
                const float* wr = w1 + (v * 4 + c) * HIDD + j0;
                #pragma unroll
                for (int jj = 0; jj < 16; ++jj) acc[jj] += r * wr[jj];
            }
        }
        #pragma unroll
        for (int jj = 0; jj < 16; ++jj) s_h1[el * 65 + j0 + jj] = silu(acc[jj]);
    }
    __syncthreads();

    // ---- phase 2: MLP layer 2 -> s_hb (bf16) ----
    {
        float acc[16];
        #pragma unroll
        for (int jj = 0; jj < 16; ++jj) acc[jj] = b2[j0 + jj];
        #pragma unroll 8
        for (int i = 0; i < HIDD; ++i) {
            float hv = s_h1[el * 65 + i];
            const float* wr = w2 + i * HIDD + j0;
            #pragma unroll
            for (int jj = 0; jj < 16; ++jj) acc[jj] += hv * wr[jj];
        }
        #pragma unroll
        for (int jj = 0; jj < 16; ++jj) s_hb[el * 72 + j0 + jj] = f2bf(silu(acc[jj]));
    }
    __syncthreads();   // s_h1 dead from here; feature region may overwrite it

    // ---- phase 3: features (transposed per-wave layouts, sh folded in) ----
    {
        const int w   = el >> 4, e16 = el & 15;
        const int src = s_src[el];
        const float sh0 = s_sh[el * 4 + 0];
        const float sh1 = s_sh[el * 4 + 1];
        const float sh2 = s_sh[el * 4 + 2];
        const float sh3 = s_sh[el * 4 + 3];
        const float* xrow = x + (size_t)src * FDIM;
        if (q < 2) {
            #pragma unroll
            for (int v = 0; v < 4; ++v) {
                f32x4 x4 = *(const f32x4*)(xrow + q * 16 + v * 4);
                #pragma unroll
                for (int c = 0; c < 4; ++c) {
                    int i = q * 16 + v * 4 + c;
                    float val = x4[c];
                    s_fsT[w * 768 + i * 16 + e16] = val * sh0;   // W1 path
                    s_xsT[w * 512 + i * 16 + e16] = val;         // W2 path
                }
            }
        } else {
            int qq = q - 2;     // 0..1, vector irreps i = qq*8 .. +8
            float buf[24];
            #pragma unroll
            for (int v = 0; v < 6; ++v) {
                f32x4 t4 = *(const f32x4*)(xrow + MUL0 + qq * 24 + v * 4);
                buf[v*4+0] = t4[0]; buf[v*4+1] = t4[1];
                buf[v*4+2] = t4[2]; buf[v*4+3] = t4[3];
            }
            #pragma unroll
            for (int ii = 0; ii < 8; ++ii) {
                int i = qq * 8 + ii;
                float v0 = buf[ii*3+0], v1 = buf[ii*3+1], v2 = buf[ii*3+2];
                s_xvT[w * 768 +   0 + i * 16 + e16] = v0 * sh0;  // W3 path (sh_s folded)
                s_xvT[w * 768 + 256 + i * 16 + e16] = v1 * sh0;
                s_xvT[w * 768 + 512 + i * 16 + e16] = v2 * sh0;
                s_fsT[w * 768 + (32 + i) * 16 + e16] =
                    C110 * (v0 * sh1 + v1 * sh2 + v2 * sh3);     // W4 path
            }
        }
    }
    __syncthreads();

    // ---- phase 4: per-wave MFMA main loop ----
    const int w  = tid >> 6;
    const int l  = tid & 63;
    const int lo = l & 15;           // output column within tile
    const int g  = l >> 4;           // row group: edges 4g..4g+3

    short8 a0 = *(const short8*)&s_hb[(16 * w + lo) * 72 + 8 * g];        // k 0..31
    short8 a1 = *(const short8*)&s_hb[(16 * w + lo) * 72 + 32 + 8 * g];   // k 32..63
    const short8* WB = (const short8*)w3b;

    f32x4 accs0 = {0.f,0.f,0.f,0.f};   // out_s, o = lo
    f32x4 accs1 = {0.f,0.f,0.f,0.f};   // out_s, o = 16+lo
    f32x4 acct2 = {0.f,0.f,0.f,0.f};   // W2 partial (xs . W2)
    f32x4 accv0 = {0.f,0.f,0.f,0.f};   // W3 partial, d=0 (sh_s folded)
    f32x4 accv1 = {0.f,0.f,0.f,0.f};
    f32x4 accv2 = {0.f,0.f,0.f,0.f};

    auto wtile = [&](int ct, int c0) -> f32x4 {
        float bc = b3[c0 + lo];
        f32x4 t = {bc, bc, bc, bc};
        t = mfma16(a0, WB[(ct * 2 + 0) * 64 + l], t);
        t = mfma16(a1, WB[(ct * 2 + 1) * 64 + l], t);
        return t;
    };

    #pragma unroll 4
    for (int i = 0; i < 32; ++i) {
        f32x4 f1 = *(const f32x4*)&s_fsT[w * 768 + i * 16 + 4 * g];
        accs0 += f1 * wtile(2 * i,     i * MUL0);
        accs1 += f1 * wtile(2 * i + 1, i * MUL0 + 16);
        f32x4 f2 = *(const f32x4*)&s_xsT[w * 512 + i * 16 + 4 * g];
        acct2 += f2 * wtile(64 + i, OFF1 + i * MUL1);
    }
    #pragma unroll 4
    for (int i = 0; i < 16; ++i) {
        f32x4 f4 = *(const f32x4*)&s_fsT[w * 768 + (32 + i) * 16 + 4 * g];
        accs0 += f4 * wtile(112 + 2 * i, OFF3 + i * MUL0);
        accs1 += f4 * wtile(113 + 2 * i, OFF3 + i * MUL0 + 16);
        f32x4 t3 = wtile(96 + i, OFF2 + i * MUL1);
        accv0 += (*(const f32x4*)&s_xvT[w * 768 +   0 + i * 16 + 4 * g]) * t3;
        accv1 += (*(const f32x4*)&s_xvT[w * 768 + 256 + i * 16 + 4 * g]) * t3;
        accv2 += (*(const f32x4*)&s_xvT[w * 768 + 512 + i * 16 + 4 * g]) * t3;
    }

    // ---- epilogue: scatter-add (lane covers 4 edges x 1 column) ----
    #pragma unroll
    for (int r = 0; r < 4; ++r) {
        int e_loc = 16 * w + 4 * g + r;
        float* row = agg + (size_t)s_dst[e_loc] * FDIM;
        atomicAdd(row + lo,      CPATH * accs0[r]);
        atomicAdd(row + 16 + lo, CPATH * accs1[r]);
        float sv0 = s_sh[e_loc * 4 + 1];
        float sv1 = s_sh[e_loc * 4 + 2];
        float sv2 = s_sh[e_loc * 4 + 3];
        atomicAdd(row + MUL0 + lo * 3 + 0, CPATH * (sv0 * acct2[r] + accv0[r]));
        atomicAdd(row + MUL0 + lo * 3 + 1, CPATH * (sv1 * acct2[r] + accv1[r]));
        atomicAdd(row + MUL0 + lo * 3 + 2, CPATH * (sv2 * acct2[r] + accv2[r]));
    }
    if (l < 16) atomicAdd(deg + s_dst[16 * w + l], 1.0f);
}

// ---------------------------------------------------------------------------
// Kernel 2: per-node epilogue, LDS-staged (no big per-thread arrays -> no spill).
// 16 nodes/block, 16 threads/node. out holds agg on entry; overwritten.
// ---------------------------------------------------------------------------
#define NPB 16
__global__ __launch_bounds__(256)
void k_node(const float* __restrict__ x,
            const float* __restrict__ deg,
            const float* __restrict__ ws_self,
            const float* __restrict__ wv_self,
            const float* __restrict__ ws_out,
            const float* __restrict__ wv_out,
            float* __restrict__ out)
{
    __shared__ float s_x[NPB][81];
    __shared__ float s_a[NPB][81];
    __shared__ float s_inv[NPB];

    const int tid = threadIdx.x;
    const int n0  = blockIdx.x * NPB;

    if (tid < NPB) s_inv[tid] = 1.0f / fmaxf(deg[n0 + tid], 1.0f);
    const float* xb = x   + (size_t)n0 * FDIM;
    const float* ab = out + (size_t)n0 * FDIM;
    for (int idx = tid; idx < NPB * FDIM; idx += 256) {
        int nl = idx / FDIM, jj = idx - nl * FDIM;
        s_x[nl][jj] = xb[idx];
        s_a[nl][jj] = ab[idx];
    }
    __syncthreads();

    const int j  = tid & 15;
    const int nl = tid >> 4;
    const float inv = s_inv[nl];
    float* orow = out + (size_t)(n0 + nl) * FDIM;

    // scalar block: outputs o = j and o = j+16
    float s1s = 0.f, s1a = 0.f, s2s = 0.f, s2a = 0.f;
    #pragma unroll
    for (int i = 0; i < MUL0; ++i) {
        float xs = s_x[nl][i], as = s_a[nl][i];
        s1s += xs * ws_self[i * MUL0 + j];
        s1a += as * ws_out [i * MUL0 + j];
        s2s += xs * ws_self[i * MUL0 + j + 16];
        s2a += as * ws_out [i * MUL0 + j + 16];
    }
    orow[j]      = s1s + inv * s1a;
    orow[j + 16] = s2s + inv * s2a;

    // vector block: output o = j (<16), 3 components
    float vs[3] = {0.f, 0.f, 0.f}, va[3] = {0.f, 0.f, 0.f};
    #pragma unroll
    for (int i = 0; i < MUL1; ++i) {
        float wsf = wv_self[i * MUL1 + j];
        float wof = wv_out [i * MUL1 + j];
        #pragma unroll
        for (int d = 0; d < 3; ++d) {
            vs[d] += s_x[nl][MUL0 + 3 * i + d] * wsf;
            va[d] += s_a[nl][MUL0 + 3 * i + d] * wof;
        }
    }
    #pragma unroll
    for (int d = 0; d < 3; ++d)
        orow[MUL0 + j * 3 + d] = vs[d] + inv * va[d];
}

// ---------------------------------------------------------------------------
extern "C" void kernel_launch(void* const* d_in, const int* in_sizes, int n_in,
                              void* d_out, int out_size, void* d_ws, size_t ws_size,
                              hipStream_t stream)
{
    const float* x       = (const float*)d_in[0];
    const int*   esrc    = (const int*)  d_in[1];
    const int*   edst    = (const int*)  d_in[2];
    const float* esh     = (const float*)d_in[3];
    const float* erbf    = (const float*)d_in[4];
    const float* w1      = (const float*)d_in[5];
    const float* b1      = (const float*)d_in[6];
    const float* w2      = (const float*)d_in[7];
    const float* b2      = (const float*)d_in[8];
    const float* w3      = (const float*)d_in[9];
    const float* b3      = (const float*)d_in[10];
    const float* ws_self = (const float*)d_in[11];
    const float* wv_self = (const float*)d_in[12];
    const float* ws_out  = (const float*)d_in[13];
    const float* wv_out  = (const float*)d_in[14];

    const int N = in_sizes[0] / FDIM;   // 50000
    const int E = in_sizes[1];          // 200000

    // ws layout: [deg: N floats][w3b: 144*2*64*8 bf16] (offset 16B-aligned)
    float* deg = (float*)d_ws;
    size_t degBytes = ((size_t)N * sizeof(float) + 255) & ~(size_t)255;
    unsigned short* w3b = (unsigned short*)((char*)d_ws + degBytes);

    hipMemsetAsync(d_out, 0, (size_t)out_size * sizeof(float), stream);
    hipMemsetAsync(deg, 0, (size_t)N * sizeof(float), stream);

    k_prep_w3b<<<(NCT * 2 * 64 * 8 + 255) / 256, 256, 0, stream>>>(w3, w3b);

    k_edge<<<E / TE, 256, 0, stream>>>(
        x, esrc, edst, esh, erbf, w1, b1, w2, b2, w3b, b3,
        (float*)d_out, deg);

    k_node<<<N / NPB, 256, 0, stream>>>(
        x, deg, ws_self, wv_self, ws_out, wv_out, (float*)d_out);
}

// Round 3
// 281.054 us; speedup vs baseline: 12.0632x; 1.3576x over previous
//
#include <hip/hip_runtime.h>
#include <math.h>

// Problem constants (fixed by reference)
#define MUL0    32
#define MUL1    16
#define RBFD    16
#define HIDD    64
#define OFF1    1024      // MUL0*MUL0
#define OFF2    1536      // +MUL0*MUL1
#define OFF3    1792      // +MUL1*MUL1
#define WNUMEL  2304      // +MUL1*MUL0
#define FDIM    80        // MUL0 + 3*MUL1
#define CPATH   0.14433756729740643f   // 1/sqrt(48)
#define C110    0.57735026918962576f   // 1/sqrt(3)

#define TE       160      // edges per block (200000/160 = 1250 exact)
#define NTHREADS 320      // 5 waves; each wave owns 32 edges (2 row-tiles)
#define NCT      144      // 2304/16 column tiles

#define W3B_ELEMS (NCT*2*64*8)     // 294912
#define W1B_ELEMS (4*64*8)         // 2048  (K=32: 16 real + 16 zero)
#define W2B_ELEMS (4*2*64*8)       // 4096  (K=64)

typedef float          f32x4   __attribute__((ext_vector_type(4)));
typedef short          short8  __attribute__((ext_vector_type(8)));
typedef short          short4v __attribute__((ext_vector_type(4)));
typedef unsigned short u16;

__device__ __forceinline__ float silu(float v) {
    return v / (1.0f + __expf(-v));
}
__device__ __forceinline__ u16 f2bf(float f) {      // RNE fp32->bf16
    unsigned int u = __float_as_uint(f);
    u += 0x7fffu + ((u >> 16) & 1u);
    return (u16)(u >> 16);
}
__device__ __forceinline__ float bf2f(u16 s) {
    return __uint_as_float(((unsigned int)s) << 16);
}
__device__ __forceinline__ f32x4 cvt4(short4v s) {
    f32x4 r;
    r[0] = bf2f((u16)s[0]); r[1] = bf2f((u16)s[1]);
    r[2] = bf2f((u16)s[2]); r[3] = bf2f((u16)s[3]);
    return r;
}
__device__ __forceinline__ f32x4 mfma16(short8 a, short8 b, f32x4 c) {
    return __builtin_amdgcn_mfma_f32_16x16x32_bf16(a, b, c, 0, 0, 0);
}

// ---------------------------------------------------------------------------
// Kernel 0: pack w3 / w1 / w2 into bf16 B-fragments.
// Fragment (64 lanes x 8 elems): lane l elem j -> k = kh*32 + 8*(l>>4)+j,
// col = ct*16 + (l&15). w3b: 144 ct x 2 kh; w1b: 4 ct x 1 (K=32, k>=16 -> 0);
// w2b: 4 ct x 2 kh.
// ---------------------------------------------------------------------------
__global__ void k_prep(const float* __restrict__ w3,
                       const float* __restrict__ w1,
                       const float* __restrict__ w2,
                       u16* __restrict__ w3b,
                       u16* __restrict__ w1b,
                       u16* __restrict__ w2b) {
    int idx = blockIdx.x * 256 + threadIdx.x;
    if (idx < W3B_ELEMS) {
        int j  = idx & 7;
        int l  = (idx >> 3) & 63;
        int kh = (idx >> 9) & 1;
        int ct = idx >> 10;
        int k = kh * 32 + 8 * (l >> 4) + j;
        int c = ct * 16 + (l & 15);
        w3b[idx] = f2bf(w3[k * WNUMEL + c]);
        return;
    }
    idx -= W3B_ELEMS;
    if (idx < W1B_ELEMS) {
        int j  = idx & 7;
        int l  = (idx >> 3) & 63;
        int ct = idx >> 9;
        int k = 8 * (l >> 4) + j;
        int c = ct * 16 + (l & 15);
        w1b[idx] = (k < RBFD) ? f2bf(w1[k * HIDD + c]) : (u16)0;
        return;
    }
    idx -= W1B_ELEMS;
    if (idx < W2B_ELEMS) {
        int j  = idx & 7;
        int l  = (idx >> 3) & 63;
        int kh = (idx >> 9) & 1;
        int ct = idx >> 10;
        int k = kh * 32 + 8 * (l >> 4) + j;
        int c = ct * 16 + (l & 15);
        w2b[idx] = f2bf(w2[k * HIDD + c]);
    }
}

// ---------------------------------------------------------------------------
// Kernel 1: MFMA MLP + fused W-tile contraction + atomic scatter.
// 5 waves x 32 edges (2 row-tiles of 16). LDS (54016 B):
//   [0,40960)  features bf16: fsT @u16 0 (grp*768+i*16+e), xsT @7680
//              (grp*512+..), xvT @12800 (grp*768+(d*16+i)*16+e)
//              ALIAS (MLP phase): s_hb [160][72] u16 (h1 then h)
//   [40960,50176) s_b3 f32[2304]; [50176,52736) s_sh [160][4];
//   [52736,54016) s_src/s_dst int[160] each
// ---------------------------------------------------------------------------
__global__ __launch_bounds__(320)
void k_edge(const float* __restrict__ x,
            const int*   __restrict__ esrc,
            const int*   __restrict__ edst,
            const float* __restrict__ esh,
            const float* __restrict__ erbf,
            const u16*   __restrict__ w1b,
            const float* __restrict__ b1,
            const u16*   __restrict__ w2b,
            const float* __restrict__ b2,
            const u16*   __restrict__ w3b,
            const float* __restrict__ b3,
            float* __restrict__ agg,
            float* __restrict__ deg)
{
    __shared__ alignas(16) unsigned char smem[54016];
    u16*   S     = (u16*)smem;
    float* s_b3  = (float*)(smem + 40960);
    float* s_sh  = (float*)(smem + 50176);
    int*   s_src = (int*)(smem + 52736);
    int*   s_dst = (int*)(smem + 53376);

    const int tid = threadIdx.x;
    const int eb  = blockIdx.x * TE;
    const int w   = tid >> 6;        // wave 0..4
    const int l   = tid & 63;
    const int lo  = l & 15;
    const int g   = l >> 4;

    // ---- stage edge metadata ----
    if (tid < TE) {
        s_src[tid] = esrc[eb + tid];
        s_dst[tid] = edst[eb + tid];
    }
    for (int idx = tid; idx < TE * 4; idx += NTHREADS)
        s_sh[idx] = esh[eb * 4 + idx];

    // bias C-init values (per column tile)
    float cb1[4], cb2[4];
    #pragma unroll
    for (int ct = 0; ct < 4; ++ct) {
        cb1[ct] = b1[ct * 16 + lo];
        cb2[ct] = b2[ct * 16 + lo];
    }

    const short8* W1B = (const short8*)w1b;
    const short8* W2B = (const short8*)w2b;

    // ---- MLP layer 1 (MFMA, K=32): rbf -> h1 (bf16 in S rows, stride 72) ----
    #pragma unroll
    for (int gr = 0; gr < 2; ++gr) {
        const int e0 = 32 * w + 16 * gr;
        short8 ar = {0, 0, 0, 0, 0, 0, 0, 0};
        if (g < 2) {
            const float* rp = erbf + (size_t)(eb + e0 + lo) * RBFD + 8 * g;
            f32x4 r0 = *(const f32x4*)rp;
            f32x4 r1 = *(const f32x4*)(rp + 4);
            ar[0] = f2bf(r0[0]); ar[1] = f2bf(r0[1]);
            ar[2] = f2bf(r0[2]); ar[3] = f2bf(r0[3]);
            ar[4] = f2bf(r1[0]); ar[5] = f2bf(r1[1]);
            ar[6] = f2bf(r1[2]); ar[7] = f2bf(r1[3]);
        }
        #pragma unroll
        for (int ct = 0; ct < 4; ++ct) {
            f32x4 t = {cb1[ct], cb1[ct], cb1[ct], cb1[ct]};
            t = mfma16(ar, W1B[ct * 64 + l], t);
            #pragma unroll
            for (int r = 0; r < 4; ++r)
                S[(e0 + 4 * g + r) * 72 + ct * 16 + lo] = f2bf(silu(t[r]));
        }
    }

    // ---- MLP layer 2 (MFMA, K=64): h1 -> h (overwrite same rows; wave-private) ----
    #pragma unroll
    for (int gr = 0; gr < 2; ++gr) {
        const int e0 = 32 * w + 16 * gr;
        short8 a0 = *(const short8*)&S[(e0 + lo) * 72 + 0  + 8 * g];
        short8 a1 = *(const short8*)&S[(e0 + lo) * 72 + 32 + 8 * g];
        #pragma unroll
        for (int ct = 0; ct < 4; ++ct) {
            f32x4 t = {cb2[ct], cb2[ct], cb2[ct], cb2[ct]};
            t = mfma16(a0, W2B[(ct * 2 + 0) * 64 + l], t);
            t = mfma16(a1, W2B[(ct * 2 + 1) * 64 + l], t);
            #pragma unroll
            for (int r = 0; r < 4; ++r)
                S[(e0 + 4 * g + r) * 72 + ct * 16 + lo] = f2bf(silu(t[r]));
        }
    }

    // ---- load main-loop A-fragments (this wave's 2 row-tiles) ----
    short8 a[2][2];
    #pragma unroll
    for (int rt = 0; rt < 2; ++rt) {
        const int e0 = 32 * w + 16 * rt;
        a[rt][0] = *(const short8*)&S[(e0 + lo) * 72 + 0  + 8 * g];
        a[rt][1] = *(const short8*)&S[(e0 + lo) * 72 + 32 + 8 * g];
    }
    __syncthreads();   // h region dead; features may overwrite

    // ---- feature build (bf16, sh folded) + b3 staging ----
    if (tid < TE) {
        const int el = tid, grp = el >> 4, e16 = el & 15;
        const float sh0 = s_sh[el * 4 + 0];
        const float sh1 = s_sh[el * 4 + 1];
        const float sh2 = s_sh[el * 4 + 2];
        const float sh3 = s_sh[el * 4 + 3];
        const float* xrow = x + (size_t)s_src[el] * FDIM;
        u16* fsB = S + grp * 768 + e16;
        u16* xsB = S + 7680  + grp * 512 + e16;
        u16* xvB = S + 12800 + grp * 768 + e16;
        #pragma unroll
        for (int v = 0; v < 8; ++v) {
            f32x4 x4 = *(const f32x4*)(xrow + 4 * v);
            #pragma unroll
            for (int c2 = 0; c2 < 4; ++c2) {
                int i = 4 * v + c2;
                fsB[i * 16] = f2bf(x4[c2] * sh0);
                xsB[i * 16] = f2bf(x4[c2]);
            }
        }
        float buf[48];
        #pragma unroll
        for (int v = 0; v < 12; ++v) {
            f32x4 t4 = *(const f32x4*)(xrow + MUL0 + 4 * v);
            buf[4*v] = t4[0]; buf[4*v+1] = t4[1];
            buf[4*v+2] = t4[2]; buf[4*v+3] = t4[3];
        }
        #pragma unroll
        for (int i = 0; i < 16; ++i) {
            float v0 = buf[3*i], v1 = buf[3*i+1], v2 = buf[3*i+2];
            xvB[(0  + i) * 16] = f2bf(v0 * sh0);
            xvB[(16 + i) * 16] = f2bf(v1 * sh0);
            xvB[(32 + i) * 16] = f2bf(v2 * sh0);
            fsB[(32 + i) * 16] = f2bf(C110 * (v0 * sh1 + v1 * sh2 + v2 * sh3));
        }
    } else {
        for (int idx = tid - TE; idx < WNUMEL; idx += NTHREADS - TE)
            s_b3[idx] = b3[idx];
    }
    __syncthreads();

    // ---- main loop: 144 column tiles, 2 row-tiles each ----
    const short8* WB = (const short8*)w3b;
    f32x4 acc[2][6];
    #pragma unroll
    for (int rt = 0; rt < 2; ++rt)
        #pragma unroll
        for (int p = 0; p < 6; ++p)
            acc[rt][p] = (f32x4){0.f, 0.f, 0.f, 0.f};

    // scalar W1 (tiles 2i,2i+1) + W2 (tile 64+i)
    for (int i = 0; i < 32; ++i) {
        if ((i & 3) == 0 && i) __builtin_amdgcn_s_barrier();  // L1-reuse pacing only
        short8 b0a = WB[(4*i + 0) * 64 + l];
        short8 b0b = WB[(4*i + 1) * 64 + l];
        short8 b1a = WB[(4*i + 2) * 64 + l];
        short8 b1b = WB[(4*i + 3) * 64 + l];
        short8 b2a = WB[(128 + 2*i) * 64 + l];
        short8 b2b = WB[(129 + 2*i) * 64 + l];
        float bs0 = s_b3[(2*i)     * 16 + lo];
        float bs1 = s_b3[(2*i + 1) * 16 + lo];
        float bs2 = s_b3[(64 + i)  * 16 + lo];
        #pragma unroll
        for (int rt = 0; rt < 2; ++rt) {
            const int fb = 2 * w + rt;
            f32x4 t0 = {bs0, bs0, bs0, bs0};
            t0 = mfma16(a[rt][0], b0a, t0); t0 = mfma16(a[rt][1], b0b, t0);
            f32x4 t1 = {bs1, bs1, bs1, bs1};
            t1 = mfma16(a[rt][0], b1a, t1); t1 = mfma16(a[rt][1], b1b, t1);
            f32x4 t2 = {bs2, bs2, bs2, bs2};
            t2 = mfma16(a[rt][0], b2a, t2); t2 = mfma16(a[rt][1], b2b, t2);
            f32x4 f1 = cvt4(*(const short4v*)&S[fb * 768 + i * 16 + 4 * g]);
            f32x4 f2 = cvt4(*(const short4v*)&S[7680 + fb * 512 + i * 16 + 4 * g]);
            acc[rt][0] += f1 * t0;
            acc[rt][1] += f1 * t1;
            acc[rt][2] += f2 * t2;
        }
    }
    // W4 (tiles 112+2i, 113+2i) + W3 (tile 96+i)
    for (int i = 0; i < 16; ++i) {
        if ((i & 3) == 0) __builtin_amdgcn_s_barrier();
        short8 b4a0 = WB[(224 + 4*i) * 64 + l];
        short8 b4a1 = WB[(225 + 4*i) * 64 + l];
        short8 b4b0 = WB[(226 + 4*i) * 64 + l];
        short8 b4b1 = WB[(227 + 4*i) * 64 + l];
        short8 b3a  = WB[(192 + 2*i) * 64 + l];
        short8 b3b  = WB[(193 + 2*i) * 64 + l];
        float bs0 = s_b3[(112 + 2*i) * 16 + lo];
        float bs1 = s_b3[(113 + 2*i) * 16 + lo];
        float bs2 = s_b3[(96 + i)    * 16 + lo];
        #pragma unroll
        for (int rt = 0; rt < 2; ++rt) {
            const int fb = 2 * w + rt;
            f32x4 t4a = {bs0, bs0, bs0, bs0};
            t4a = mfma16(a[rt][0], b4a0, t4a); t4a = mfma16(a[rt][1], b4a1, t4a);
            f32x4 t4b = {bs1, bs1, bs1, bs1};
            t4b = mfma16(a[rt][0], b4b0, t4b); t4b = mfma16(a[rt][1], b4b1, t4b);
            f32x4 t3 = {bs2, bs2, bs2, bs2};
            t3 = mfma16(a[rt][0], b3a, t3); t3 = mfma16(a[rt][1], b3b, t3);
            f32x4 f4 = cvt4(*(const short4v*)&S[fb * 768 + (32 + i) * 16 + 4 * g]);
            f32x4 v0 = cvt4(*(const short4v*)&S[12800 + fb * 768 + (0  + i) * 16 + 4 * g]);
            f32x4 v1 = cvt4(*(const short4v*)&S[12800 + fb * 768 + (16 + i) * 16 + 4 * g]);
            f32x4 v2 = cvt4(*(const short4v*)&S[12800 + fb * 768 + (32 + i) * 16 + 4 * g]);
            acc[rt][0] += f4 * t4a;
            acc[rt][1] += f4 * t4b;
            acc[rt][3] += v0 * t3;
            acc[rt][4] += v1 * t3;
            acc[rt][5] += v2 * t3;
        }
    }

    // ---- epilogue: atomic scatter (lane covers 2 rt x 4 edges x 1 col) ----
    #pragma unroll
    for (int rt = 0; rt < 2; ++rt) {
        #pragma unroll
        for (int r = 0; r < 4; ++r) {
            const int e_loc = 32 * w + 16 * rt + 4 * g + r;
            float* row = agg + (size_t)s_dst[e_loc] * FDIM;
            atomicAdd(row + lo,      CPATH * acc[rt][0][r]);
            atomicAdd(row + 16 + lo, CPATH * acc[rt][1][r]);
            float sv0 = s_sh[e_loc * 4 + 1];
            float sv1 = s_sh[e_loc * 4 + 2];
            float sv2 = s_sh[e_loc * 4 + 3];
            atomicAdd(row + MUL0 + lo * 3 + 0, CPATH * (sv0 * acc[rt][2][r] + acc[rt][3][r]));
            atomicAdd(row + MUL0 + lo * 3 + 1, CPATH * (sv1 * acc[rt][2][r] + acc[rt][4][r]));
            atomicAdd(row + MUL0 + lo * 3 + 2, CPATH * (sv2 * acc[rt][2][r] + acc[rt][5][r]));
        }
    }
    if (tid < TE) atomicAdd(deg + s_dst[tid], 1.0f);
}

// ---------------------------------------------------------------------------
// Kernel 2: per-node epilogue (unchanged from R2 — ~1% of runtime).
// ---------------------------------------------------------------------------
#define NPB 16
__global__ __launch_bounds__(256)
void k_node(const float* __restrict__ x,
            const float* __restrict__ deg,
            const float* __restrict__ ws_self,
            const float* __restrict__ wv_self,
            const float* __restrict__ ws_out,
            const float* __restrict__ wv_out,
            float* __restrict__ out)
{
    __shared__ float s_x[NPB][81];
    __shared__ float s_a[NPB][81];
    __shared__ float s_inv[NPB];

    const int tid = threadIdx.x;
    const int n0  = blockIdx.x * NPB;

    if (tid < NPB) s_inv[tid] = 1.0f / fmaxf(deg[n0 + tid], 1.0f);
    const float* xb = x   + (size_t)n0 * FDIM;
    const float* ab = out + (size_t)n0 * FDIM;
    for (int idx = tid; idx < NPB * FDIM; idx += 256) {
        int nl = idx / FDIM, jj = idx - nl * FDIM;
        s_x[nl][jj] = xb[idx];
        s_a[nl][jj] = ab[idx];
    }
    __syncthreads();

    const int j  = tid & 15;
    const int nl = tid >> 4;
    const float inv = s_inv[nl];
    float* orow = out + (size_t)(n0 + nl) * FDIM;

    float s1s = 0.f, s1a = 0.f, s2s = 0.f, s2a = 0.f;
    #pragma unroll
    for (int i = 0; i < MUL0; ++i) {
        float xs = s_x[nl][i], as = s_a[nl][i];
        s1s += xs * ws_self[i * MUL0 + j];
        s1a += as * ws_out [i * MUL0 + j];
        s2s += xs * ws_self[i * MUL0 + j + 16];
        s2a += as * ws_out [i * MUL0 + j + 16];
    }
    orow[j]      = s1s + inv * s1a;
    orow[j + 16] = s2s + inv * s2a;

    float vs[3] = {0.f, 0.f, 0.f}, va[3] = {0.f, 0.f, 0.f};
    #pragma unroll
    for (int i = 0; i < MUL1; ++i) {
        float wsf = wv_self[i * MUL1 + j];
        float wof = wv_out [i * MUL1 + j];
        #pragma unroll
        for (int d = 0; d < 3; ++d) {
            vs[d] += s_x[nl][MUL0 + 3 * i + d] * wsf;
            va[d] += s_a[nl][MUL0 + 3 * i + d] * wof;
        }
    }
    #pragma unroll
    for (int d = 0; d < 3; ++d)
        orow[MUL0 + j * 3 + d] = vs[d] + inv * va[d];
}

// ---------------------------------------------------------------------------
extern "C" void kernel_launch(void* const* d_in, const int* in_sizes, int n_in,
                              void* d_out, int out_size, void* d_ws, size_t ws_size,
                              hipStream_t stream)
{
    const float* x       = (const float*)d_in[0];
    const int*   esrc    = (const int*)  d_in[1];
    const int*   edst    = (const int*)  d_in[2];
    const float* esh     = (const float*)d_in[3];
    const float* erbf    = (const float*)d_in[4];
    const float* w1      = (const float*)d_in[5];
    const float* b1      = (const float*)d_in[6];
    const float* w2      = (const float*)d_in[7];
    const float* b2      = (const float*)d_in[8];
    const float* w3      = (const float*)d_in[9];
    const float* b3      = (const float*)d_in[10];
    const float* ws_self = (const float*)d_in[11];
    const float* wv_self = (const float*)d_in[12];
    const float* ws_out  = (const float*)d_in[13];
    const float* wv_out  = (const float*)d_in[14];

    const int N = in_sizes[0] / FDIM;   // 50000
    const int E = in_sizes[1];          // 200000

    // ws layout: [deg: N f32 | w3b | w1b | w2b] (256B-aligned chunks)
    char* wsp = (char*)d_ws;
    float* deg = (float*)wsp;
    size_t off = ((size_t)N * sizeof(float) + 255) & ~(size_t)255;
    u16* w3b = (u16*)(wsp + off);
    off += ((size_t)W3B_ELEMS * 2 + 255) & ~(size_t)255;
    u16* w1b = (u16*)(wsp + off);
    off += ((size_t)W1B_ELEMS * 2 + 255) & ~(size_t)255;
    u16* w2b = (u16*)(wsp + off);

    hipMemsetAsync(d_out, 0, (size_t)out_size * sizeof(float), stream);
    hipMemsetAsync(deg, 0, (size_t)N * sizeof(float), stream);

    k_prep<<<(W3B_ELEMS + W1B_ELEMS + W2B_ELEMS + 255) / 256, 256, 0, stream>>>(
        w3, w1, w2, w3b, w1b, w2b);

    k_edge<<<E / TE, NTHREADS, 0, stream>>>(
        x, esrc, edst, esh, erbf, w1b, b1, w2b, b2, w3b, b3,
        (float*)d_out, deg);

    k_node<<<N / NPB, 256, 0, stream>>>(
        x, deg, ws_self, wv_self, ws_out, wv_out, (float*)d_out);
}